// Round 17
// baseline (189.570 us; speedup 1.0000x reference)
//
#include <hip/hip_runtime.h>
#include <hip/hip_fp16.h>

#define N_PTS 100000
#define MU_F  100.0f

typedef unsigned int uint;
typedef _Float16 h2 __attribute__((ext_vector_type(2)));
typedef float f2 __attribute__((ext_vector_type(2)));

#define E_SCALE 16384.0f
#define E_SCALE_INV (1.0f / 16384.0f)

static __device__ inline h2 h2pack(float a, float b) {
    return __builtin_bit_cast(h2, __builtin_amdgcn_cvt_pkrtz(a, b));
}
static __device__ inline float fdot2f(h2 a, h2 b, float c) {
    return __builtin_amdgcn_fdot2(a, b, c, false);
}
static __device__ inline h2 h2fma(h2 a, h2 b, h2 c) {
#if __has_builtin(__builtin_elementwise_fma)
    return __builtin_elementwise_fma(a, b, c);
#else
    return a * b + c;
#endif
}
static __device__ inline h2 h2max(h2 a, h2 b) {
#if __has_builtin(__builtin_elementwise_max)
    return __builtin_elementwise_max(a, b);
#else
    h2 r;
    r.x = a.x > b.x ? a.x : b.x;
    r.y = a.y > b.y ? a.y : b.y;
    return r;
#endif
}

#define ENC_BLKS 256
#define TR_BLKS  1563            // ceil(100000/64)
#define S_BLKS   1024
#define S_PCH    98              // ceil(100000/1024)
#define S_PAD    104             // pInv coverage
#define NCOPY    8               // S replication factor
#define NPAIRS   (N_PTS / 2)     // 50000
#define M_BLKS   1024
#define M_CH     49              // ceil(50000/1024) pairs per block

// ws layout (memset zeroes [0,32896): enc + S8):
//   [0,128)         enc (32 f, atomicAdd target)
//   [128,32896)     S8 (8 x 1024 f, replicated atomicAdd target)
//   [32896,34944)   invFG (512 f)
//   [34944,35968)   invHLG2 (256 h2) [h][c][q][t2]: h*128+c*8+q*2+t2,
//                   i0 = h*16+q*4+2*t2
//   [532480,3732480)  decL (N x 16 fp16, 3.2 MB, i 0..15)
//   [3732480,6932480) decH (N x 16 fp16, 3.2 MB, i 16..31)
// Round-16 post-mortem: k_main's FETCH 96.5MB vs ~33MB ideal == ~70MB of
// decT(6.4MB > 4MB/XCD L2) capacity re-fetch. Fix (round-12's idea done
// right): TWO PASSES INSIDE ONE KERNEL — pass-lo gathers only decL (3.2MB,
// L2-resident), parks per-j wave-reduced partials in LDS (392B); pass-hi
// gathers decH, adds, stores. No extra dispatch, 2nd-pass nd/nid re-reads
// are L2-hot. NO cross-block fences (round-7); atomics device-scope.

// ---------------------------------------------------------------------------
// K1: encode (256 blocks) || dec transpose -> decL/decH (1563 blocks).
// ---------------------------------------------------------------------------
__global__ __launch_bounds__(256) void k_prep_tr(const float* __restrict__ x,
                                                 const float* __restrict__ encW,
                                                 const float* __restrict__ encB,
                                                 float* __restrict__ enc,
                                                 const float* __restrict__ dec,
                                                 __half* __restrict__ decL,
                                                 __half* __restrict__ decH) {
    int b = blockIdx.x;
    if (b < ENC_BLKS) {
        int row = b & 31;
        int chunk = b >> 5;              // 0..7
        const int CH = N_PTS / 8;        // 12500
        int base = chunk * CH;
        const float4* W4 = reinterpret_cast<const float4*>(encW + (size_t)row * N_PTS + base);
        const float4* x4 = reinterpret_cast<const float4*>(x + base);
        const int nv = CH / 4;           // 3125
        float acc = 0.f;
        for (int idx = threadIdx.x; idx < nv; idx += 256) {
            float4 w = W4[idx];
            float4 xv = x4[idx];
            acc += w.x * xv.x + w.y * xv.y + w.z * xv.z + w.w * xv.w;
        }
        #pragma unroll
        for (int off = 32; off > 0; off >>= 1) acc += __shfl_down(acc, off);
        __shared__ float sred[4];
        int wid = threadIdx.x >> 6;
        if ((threadIdx.x & 63) == 0) sred[wid] = acc;
        __syncthreads();
        if (threadIdx.x == 0) {
            float s = sred[0] + sred[1] + sred[2] + sred[3];
            if (chunk == 0) s += encB[row];
            atomicAdd(enc + row, s);
        }
    } else {
        // ----- transpose dec [32,N] f32 -> decL/decH [N,16] fp16 (32B rows)
        __shared__ float tile[32][65];
        int j0 = (b - ENC_BLKS) * 64;
        int col = threadIdx.x & 63;
        int r0 = threadIdx.x >> 6;       // 0..3
        #pragma unroll
        for (int it = 0; it < 8; ++it) {
            int row = it * 4 + r0;
            int j = j0 + col;
            float v = (j < N_PTS) ? dec[(size_t)row * N_PTS + j] : 0.f;
            tile[row][col] = v;
        }
        __syncthreads();
        #pragma unroll
        for (int it = 0; it < 4; ++it) {
            int idx = it * 256 + threadIdx.x;
            int j = idx >> 4;            // 0..63
            int p = idx & 15;            // i-pair 0..15
            int jj = j0 + j;
            if (jj < N_PTS) {
                __half2 h = __halves2half2(__float2half(tile[2 * p][j]),
                                           __float2half(tile[2 * p + 1][j]));
                __half* dst = (p < 8) ? (decL + (size_t)jj * 16 + 2 * p)
                                      : (decH + (size_t)jj * 16 + 2 * (p - 8));
                *reinterpret_cast<__half2*>(dst) = h;
            }
        }
    }
}

// ---------------------------------------------------------------------------
// K_tab (1 block): build invFG[512] (f32) and invHLG2[256] (packed h2) ONCE.
// invF[c*32+i] = 1/(sigmoid(enc.bw_w[i*16+c]+b)*MU/60)^2
// invHLG2[t]: t = h*128 + c*8 + q*2 + t2, i0 = h*16 + q*4 + 2*t2.
// ---------------------------------------------------------------------------
__global__ __launch_bounds__(256) void k_tab(const float* __restrict__ enc_g,
                                             const float* __restrict__ bw_w,
                                             const float* __restrict__ bw_b,
                                             float* __restrict__ invFG,
                                             h2* __restrict__ invHLG2) {
    __shared__ float encL[32];
    __shared__ float invF[512];
    if (threadIdx.x < 32) encL[threadIdx.x] = enc_g[threadIdx.x];
    __syncthreads();
    for (int r = threadIdx.x; r < 512; r += 256) {
        int i = r >> 4, c = r & 15;
        const float4* wr4 = reinterpret_cast<const float4*>(bw_w + (size_t)r * 32);
        float z = bw_b[r];
        #pragma unroll
        for (int p4 = 0; p4 < 8; ++p4) {
            float4 wv = wr4[p4];
            z = fmaf(encL[4 * p4 + 0], wv.x, z);
            z = fmaf(encL[4 * p4 + 1], wv.y, z);
            z = fmaf(encL[4 * p4 + 2], wv.z, z);
            z = fmaf(encL[4 * p4 + 3], wv.w, z);
        }
        float s = 1.f / (1.f + __expf(-z));
        float wmu = s * (MU_F / 60.0f);
        float iv = 1.f / (wmu * wmu);
        invF[c * 32 + i] = iv;
        invFG[c * 32 + i] = iv;
    }
    __syncthreads();
    {
        int t = threadIdx.x;             // 2h x 16c x 4q x 2t2
        int hh = t >> 7, c = (t >> 3) & 15, qq = (t >> 1) & 3, t2 = t & 1;
        int i0 = hh * 16 + qq * 4 + 2 * t2;
        invHLG2[t] = h2pack(fminf(invF[c * 32 + i0], 6.0e4f),
                            fminf(invF[c * 32 + i0 + 1], 6.0e4f));
    }
}

// ---------------------------------------------------------------------------
// K2: S pass with pre-materialized pInv (round-16, measured ok). Epilogue:
// NCOPY=8 replicated atomicAdd (round-11 contention fix).
// ---------------------------------------------------------------------------
__global__ __launch_bounds__(256, 8) void k_S(const float* __restrict__ invFG,
                                              const float* __restrict__ nd,
                                              const int* __restrict__ labels,
                                              float* __restrict__ S8) {
    __shared__ float invF[512];
    __shared__ int   labL[S_PAD];
    __shared__ float pInv[S_PAD * 32];   // 13KB
    int t = threadIdx.x;
    int start = blockIdx.x * S_PCH;
    int jend = min(start + S_PCH, N_PTS);
    int npts = jend - start;

    if (t < 128)
        reinterpret_cast<float4*>(invF)[t] =
            reinterpret_cast<const float4*>(invFG)[t];
    if (npts > 0 && t < S_PAD) {
        int jc = min(t, npts - 1);
        labL[t] = labels[start + jc];
    }
    __syncthreads();
    if (npts > 0) {
        for (int e = t; e < S_PAD * 32; e += 256) {
            int j = e >> 5, kk = e & 31;
            pInv[e] = invF[labL[j] * 32 + kk];
        }
    }
    __syncthreads();
    if (npts <= 0) return;

    int kk = t & 31;
    int ig = t >> 5;                     // 0..7
    float a0 = 0.f, a1 = 0.f, a2 = 0.f, a3 = 0.f;

    auto ld4d = [&](int jbase, float* d) {
        #pragma unroll
        for (int u = 0; u < 4; ++u) {
            int j = jbase + u;
            int jc = min(j, N_PTS - 1);
            float dv = __builtin_nontemporal_load(&nd[(size_t)jc * 32 + kk]);
            d[u] = (j < jend) ? dv : 1.0e15f;   // pad -> w == 0 exactly
        }
    };
    float dA[4], dB[4], dC[4];
    ld4d(start, dA);
    ld4d(start + 4, dB);
    for (int jj = start; jj < jend; jj += 4) {
        ld4d(jj + 8, dC);
        int base = (jj - start) * 32 + ig * 4;
        #pragma unroll
        for (int u = 0; u < 4; ++u) {
            float4 iv = *reinterpret_cast<const float4*>(&pInv[base + u * 32]);
            float d2 = dA[u] * dA[u];
            a0 += fmaxf(fmaf(d2, -iv.x, 1.f), 0.f);
            a1 += fmaxf(fmaf(d2, -iv.y, 1.f), 0.f);
            a2 += fmaxf(fmaf(d2, -iv.z, 1.f), 0.f);
            a3 += fmaxf(fmaf(d2, -iv.w, 1.f), 0.f);
        }
        #pragma unroll
        for (int u = 0; u < 4; ++u) { dA[u] = dB[u]; dB[u] = dC[u]; }
    }

    float* Sc = S8 + (size_t)(blockIdx.x & (NCOPY - 1)) * 1024;
    int cell = (ig * 4) * 32 + kk;
    atomicAdd(&Sc[cell], a0);
    atomicAdd(&Sc[cell + 32], a1);
    atomicAdd(&Sc[cell + 64], a2);
    atomicAdd(&Sc[cell + 96], a3);
}

// ---------------------------------------------------------------------------
// K4 (main): TWO-PASS single kernel. Pass h gathers only decL/decH (3.2MB,
// per-XCD-L2-resident). Lane (R=lane>>2, q=lane&3): nid/nd slots as before;
// gather uint2 (8B) = i ∈ {h*16+q*4 .. +3}. Pass-lo parks wave-reduced
// per-j partials in LDS part[] (wave-private slots, no barrier needed);
// pass-hi adds and stores. nd/nid re-read in pass-hi is L2-hot.
// ---------------------------------------------------------------------------
__global__ __launch_bounds__(256, 4) void k_main(const h2* __restrict__ invHLG2,
                                                 const float* __restrict__ enc_g,
                                                 const float* __restrict__ S8,
                                                 const float* __restrict__ nd,
                                                 const int* __restrict__ nid,
                                                 const int* __restrict__ labels,
                                                 const __half* __restrict__ decL,
                                                 const __half* __restrict__ decH,
                                                 float* __restrict__ out) {
    __shared__ h2 invHL2[256];           // [h][c][q][t2]
    __shared__ float Sred[1024];
    __shared__ float part[2 * M_CH + 8]; // per-j pass-lo partials (wave-private)
    if (threadIdx.x < 64)                // 1KB coalesced copy
        reinterpret_cast<uint4*>(invHL2)[threadIdx.x] =
            reinterpret_cast<const uint4*>(invHLG2)[threadIdx.x];
    for (int t = threadIdx.x; t < 1024; t += 256) {
        float s = 0.f;
        #pragma unroll
        for (int c = 0; c < NCOPY; ++c)
            s += S8[(size_t)c * 1024 + t];
        Sred[t] = s;
    }
    __syncthreads();

    int lane = threadIdx.x & 63;
    int R = lane >> 2;                   // 0..15 (kk sub-index)
    int q = lane & 3;                    // i sub-quad within half

    // per-thread E tables, per pass: i0 = h*16 + q*4 + 2*t2.
    h2 EA0[2], EB0[2], EA1[2], EB1[2];
    #pragma unroll
    for (int hh = 0; hh < 2; ++hh) {
        #pragma unroll
        for (int t2 = 0; t2 < 2; ++t2) {
            int i0 = hh * 16 + q * 4 + 2 * t2;
            float e0 = enc_g[i0], e1 = enc_g[i0 + 1];
            float sA0 = Sred[i0 * 32 + R],      sA1 = Sred[(i0 + 1) * 32 + R];
            float sB0 = Sred[i0 * 32 + R + 16], sB1 = Sred[(i0 + 1) * 32 + R + 16];
            h2 ea = h2pack(e0 / sA0 * E_SCALE, e1 / sA1 * E_SCALE);
            h2 eb = h2pack(e0 / sB0 * E_SCALE, e1 / sB1 * E_SCALE);
            if (hh == 0) { EA0[t2] = ea; EB0[t2] = eb; }
            else         { EA1[t2] = ea; EB1[t2] = eb; }
        }
    }
    const h2 zero2 = h2pack(0.f, 0.f);
    const h2 one2 = h2pack(1.f, 1.f);

    int w = threadIdx.x >> 6;            // wave 0..3
    int start = blockIdx.x * M_CH;
    int pend = min(start + M_CH, NPAIRS);

    auto load_ldd = [&](int jp0, int jp1, int* id, float* dd) {
        #pragma unroll
        for (int s = 0; s < 4; ++s) {
            size_t idx = (size_t)((s >> 1) ? jp1 : jp0) * 32 + (s & 1) * 16 + R;
            id[s] = __builtin_nontemporal_load(&nid[idx]);
            dd[s] = __builtin_nontemporal_load(&nd[idx]);
        }
    };

    auto run_pass = [&](const uint2* decQ2, const h2* ihTab,
                        const h2* EA, const h2* EB, bool first) {
        for (int p = start + w; p < pend; p += 8) {
            bool has2 = (p + 4) < pend;
            int p2 = has2 ? (p + 4) : p;
            int jA0 = 2 * p,  jA1 = jA0 + 1;
            int jB0 = 2 * p2, jB1 = jB0 + 1;

            int cA0 = labels[jA0], cA1 = labels[jA1];
            int cB0 = labels[jB0], cB1 = labels[jB1];
            int idA[4], idB[4]; float ddA[4], ddB[4];
            load_ldd(jA0, jA1, idA, ddA);
            load_ldd(jB0, jB1, idB, ddB);
            uint2 rA[4], rB[4];
            #pragma unroll
            for (int s = 0; s < 4; ++s) {
                rA[s] = decQ2[(size_t)idA[s] * 4 + q];
                rB[s] = decQ2[(size_t)idB[s] * 4 + q];
            }
            h2 ihA0[2], ihA1[2], ihB0[2], ihB1[2];
            {
                uint2 a = *reinterpret_cast<const uint2*>(&ihTab[cA0 * 8 + q * 2]);
                uint2 b2 = *reinterpret_cast<const uint2*>(&ihTab[cA1 * 8 + q * 2]);
                uint2 cc = *reinterpret_cast<const uint2*>(&ihTab[cB0 * 8 + q * 2]);
                uint2 dd2 = *reinterpret_cast<const uint2*>(&ihTab[cB1 * 8 + q * 2]);
                ihA0[0] = __builtin_bit_cast(h2, a.x);  ihA0[1] = __builtin_bit_cast(h2, a.y);
                ihA1[0] = __builtin_bit_cast(h2, b2.x); ihA1[1] = __builtin_bit_cast(h2, b2.y);
                ihB0[0] = __builtin_bit_cast(h2, cc.x); ihB0[1] = __builtin_bit_cast(h2, cc.y);
                ihB1[0] = __builtin_bit_cast(h2, dd2.x); ihB1[1] = __builtin_bit_cast(h2, dd2.y);
            }

            h2 mdA0, mdA1, mdA2, mdA3, mdB0, mdB1, mdB2, mdB3;
            {
                float d0 = ddA[0] * ddA[0], d1 = ddA[1] * ddA[1];
                float d2 = ddA[2] * ddA[2], d3 = ddA[3] * ddA[3];
                mdA0 = h2pack(-d0, -d0); mdA1 = h2pack(-d1, -d1);
                mdA2 = h2pack(-d2, -d2); mdA3 = h2pack(-d3, -d3);
                float e0 = ddB[0] * ddB[0], e1 = ddB[1] * ddB[1];
                float e2 = ddB[2] * ddB[2], e3 = ddB[3] * ddB[3];
                mdB0 = h2pack(-e0, -e0); mdB1 = h2pack(-e1, -e1);
                mdB2 = h2pack(-e2, -e2); mdB3 = h2pack(-e3, -e3);
            }

            float a0 = 0.f, a1 = 0.f, a2 = 0.f, a3 = 0.f;
            float b0 = 0.f, b1 = 0.f, b2 = 0.f, b3 = 0.f;
            #pragma unroll
            for (int t2 = 0; t2 < 2; ++t2) {
                uint wA0 = t2 ? rA[0].y : rA[0].x;
                uint wA1 = t2 ? rA[1].y : rA[1].x;
                uint wA2 = t2 ? rA[2].y : rA[2].x;
                uint wA3 = t2 ? rA[3].y : rA[3].x;
                uint wB0 = t2 ? rB[0].y : rB[0].x;
                uint wB1 = t2 ? rB[1].y : rB[1].x;
                uint wB2 = t2 ? rB[2].y : rB[2].x;
                uint wB3 = t2 ? rB[3].y : rB[3].x;
                {
                    h2 wv = h2max(h2fma(mdA0, ihA0[t2], one2), zero2);
                    a0 = fdot2f(wv * EA[t2], __builtin_bit_cast(h2, wA0), a0);
                }
                {
                    h2 wv = h2max(h2fma(mdA1, ihA0[t2], one2), zero2);
                    a1 = fdot2f(wv * EB[t2], __builtin_bit_cast(h2, wA1), a1);
                }
                {
                    h2 wv = h2max(h2fma(mdA2, ihA1[t2], one2), zero2);
                    a2 = fdot2f(wv * EA[t2], __builtin_bit_cast(h2, wA2), a2);
                }
                {
                    h2 wv = h2max(h2fma(mdA3, ihA1[t2], one2), zero2);
                    a3 = fdot2f(wv * EB[t2], __builtin_bit_cast(h2, wA3), a3);
                }
                {
                    h2 wv = h2max(h2fma(mdB0, ihB0[t2], one2), zero2);
                    b0 = fdot2f(wv * EA[t2], __builtin_bit_cast(h2, wB0), b0);
                }
                {
                    h2 wv = h2max(h2fma(mdB1, ihB0[t2], one2), zero2);
                    b1 = fdot2f(wv * EB[t2], __builtin_bit_cast(h2, wB1), b1);
                }
                {
                    h2 wv = h2max(h2fma(mdB2, ihB1[t2], one2), zero2);
                    b2 = fdot2f(wv * EA[t2], __builtin_bit_cast(h2, wB2), b2);
                }
                {
                    h2 wv = h2max(h2fma(mdB3, ihB1[t2], one2), zero2);
                    b3 = fdot2f(wv * EB[t2], __builtin_bit_cast(h2, wB3), b3);
                }
            }
            float u = a0 + a1;               // jA0 partial (this i-half)
            float v = a2 + a3;               // jA1
            float u2 = b0 + b1;              // jB0
            float v2 = b2 + b3;              // jB1
            #pragma unroll
            for (int off = 32; off > 0; off >>= 1) {
                u += __shfl_xor(u, off);
                v += __shfl_xor(v, off);
                u2 += __shfl_xor(u2, off);
                v2 += __shfl_xor(v2, off);
            }
            int ia = jA0 - 2 * start;
            int ib = jB0 - 2 * start;
            if (first) {
                if (lane == 0)  { part[ia] = u;      part[ib] = u2; }
                if (lane == 32) { part[ia + 1] = v;  part[ib + 1] = v2; }
            } else {
                if (lane == 0) {
                    out[jA0] = (u + part[ia]) * E_SCALE_INV;
                    if (has2) out[jB0] = (u2 + part[ib]) * E_SCALE_INV;
                }
                if (lane == 32) {
                    out[jA1] = (v + part[ia + 1]) * E_SCALE_INV;
                    if (has2) out[jB1] = (v2 + part[ib + 1]) * E_SCALE_INV;
                }
            }
        }
    };

    run_pass(reinterpret_cast<const uint2*>(decL), invHL2,       EA0, EB0, true);
    run_pass(reinterpret_cast<const uint2*>(decH), invHL2 + 128, EA1, EB1, false);
}

// ---------------------------------------------------------------------------
extern "C" void kernel_launch(void* const* d_in, const int* in_sizes, int n_in,
                              void* d_out, int out_size, void* d_ws, size_t ws_size,
                              hipStream_t stream) {
    const float* x     = (const float*)d_in[0];
    const float* enc_w = (const float*)d_in[1];
    const float* enc_b = (const float*)d_in[2];
    const float* dec   = (const float*)d_in[3];
    const float* bw_w  = (const float*)d_in[4];
    const float* bw_b  = (const float*)d_in[5];
    const float* nd    = (const float*)d_in[6];
    const int*   nid   = (const int*)d_in[7];
    const int*   labels= (const int*)d_in[8];
    float* out = (float*)d_out;

    char* ws = (char*)d_ws;
    float* enc     = (float*)(ws + 0);
    float* S8      = (float*)(ws + 128);
    float* invFG   = (float*)(ws + 32896);
    h2*    invHLG2 = (h2*)(ws + 34944);
    __half* decL   = (__half*)(ws + 532480);
    __half* decH   = (__half*)(ws + 3732480);

    (void)hipMemsetAsync(d_ws, 0, 32896, stream);    // enc + S8
    k_prep_tr<<<dim3(ENC_BLKS + TR_BLKS), dim3(256), 0, stream>>>(
        x, enc_w, enc_b, enc, dec, decL, decH);
    k_tab<<<dim3(1), dim3(256), 0, stream>>>(enc, bw_w, bw_b, invFG, invHLG2);
    k_S<<<dim3(S_BLKS), dim3(256), 0, stream>>>(invFG, nd, labels, S8);
    k_main<<<dim3(M_BLKS), dim3(256), 0, stream>>>(invHLG2, enc, S8, nd, nid,
                                                   labels, decL, decH, out);
}

// Round 18
// 167.391 us; speedup vs baseline: 1.1325x; 1.1325x over previous
//
#include <hip/hip_runtime.h>
#include <hip/hip_fp16.h>

#define N_PTS 100000
#define MU_F  100.0f

typedef unsigned int uint;
typedef _Float16 h2 __attribute__((ext_vector_type(2)));
typedef float f2 __attribute__((ext_vector_type(2)));

#define E_SCALE 16384.0f
#define E_SCALE_INV (1.0f / 16384.0f)

static __device__ inline h2 h2pack(float a, float b) {
    return __builtin_bit_cast(h2, __builtin_amdgcn_cvt_pkrtz(a, b));
}
static __device__ inline float fdot2f(h2 a, h2 b, float c) {
    return __builtin_amdgcn_fdot2(a, b, c, false);
}
static __device__ inline h2 h2fma(h2 a, h2 b, h2 c) {
#if __has_builtin(__builtin_elementwise_fma)
    return __builtin_elementwise_fma(a, b, c);
#else
    return a * b + c;
#endif
}
static __device__ inline h2 h2max(h2 a, h2 b) {
#if __has_builtin(__builtin_elementwise_max)
    return __builtin_elementwise_max(a, b);
#else
    h2 r;
    r.x = a.x > b.x ? a.x : b.x;
    r.y = a.y > b.y ? a.y : b.y;
    return r;
#endif
}

#define ENC_BLKS 256
#define TR_BLKS  1563            // ceil(100000/64)
#define S_BLKS   1024
#define S_PCH    98              // ceil(100000/1024)
#define NCOPY    8               // S replication factor
#define NPAIRS   (N_PTS / 2)     // 50000
#define M_BLKS   1024
#define M_CH     49              // ceil(50000/1024) pairs per block

// ws layout (memset zeroes [0,32896): enc + S8):
//   [0,128)         enc (32 f, atomicAdd target)
//   [128,32896)     S8 (8 x 1024 f, replicated atomicAdd target)
//   [32896,34944)   invFG (512 f)
//   [34944,35968)   invHLG (256 h2)
//   [532480,...)    decT (N*32 fp16, 6.4 MB)
// ROUND-17 POST-MORTEM (final structure decision): this is the round-13
// kernel, the measured session best (167.8us). Refuted alternatives:
//  - fp8 dec table (r15): absmax 9.06e-6 > 6.90e-6 threshold, irreducible.
//  - i-split across dispatches (r12): duplicated stream reads lose ~15us.
//  - i-split fused two-pass (r17): blocks not phase-synced -> both half-
//    tables live concurrently in L2 -> FETCH unchanged, +20us fixed costs.
//  - dispatch-chain collapse 7->3 (r14): neutral (gaps are small).
//  - k_S pInv pre-materialization (r16): neutral (k_S already at floor).
//  - occupancy/ILP sweeps on k_main (r8/r9/r11/r13): best is this config.
// k_main is bound by ~70MB of intrinsic L2-capacity-miss gather traffic
// (decT 6.4MB > 4MB/XCD L2) — structural at fp16 row size.
// NO cross-block fences (round-7 lesson); atomics are device-scope.

// ---------------------------------------------------------------------------
// K1: encode (256 blocks) || dec transpose (1563 blocks) — independent leaves.
// ---------------------------------------------------------------------------
__global__ __launch_bounds__(256) void k_prep_tr(const float* __restrict__ x,
                                                 const float* __restrict__ encW,
                                                 const float* __restrict__ encB,
                                                 float* __restrict__ enc,
                                                 const float* __restrict__ dec,
                                                 __half* __restrict__ decT) {
    int b = blockIdx.x;
    if (b < ENC_BLKS) {
        int row = b & 31;
        int chunk = b >> 5;              // 0..7
        const int CH = N_PTS / 8;        // 12500
        int base = chunk * CH;
        const float4* W4 = reinterpret_cast<const float4*>(encW + (size_t)row * N_PTS + base);
        const float4* x4 = reinterpret_cast<const float4*>(x + base);
        const int nv = CH / 4;           // 3125
        float acc = 0.f;
        for (int idx = threadIdx.x; idx < nv; idx += 256) {
            float4 w = W4[idx];
            float4 xv = x4[idx];
            acc += w.x * xv.x + w.y * xv.y + w.z * xv.z + w.w * xv.w;
        }
        #pragma unroll
        for (int off = 32; off > 0; off >>= 1) acc += __shfl_down(acc, off);
        __shared__ float sred[4];
        int wid = threadIdx.x >> 6;
        if ((threadIdx.x & 63) == 0) sred[wid] = acc;
        __syncthreads();
        if (threadIdx.x == 0) {
            float s = sred[0] + sred[1] + sred[2] + sred[3];
            if (chunk == 0) s += encB[row];
            atomicAdd(enc + row, s);
        }
    } else {
        // ----- transpose dec [32,N] f32 -> decT [N,32] fp16 (64B rows)
        __shared__ float tile[32][65];
        int j0 = (b - ENC_BLKS) * 64;
        int col = threadIdx.x & 63;
        int r0 = threadIdx.x >> 6;       // 0..3
        #pragma unroll
        for (int it = 0; it < 8; ++it) {
            int row = it * 4 + r0;
            int j = j0 + col;
            float v = (j < N_PTS) ? dec[(size_t)row * N_PTS + j] : 0.f;
            tile[row][col] = v;
        }
        __syncthreads();
        #pragma unroll
        for (int it = 0; it < 4; ++it) {
            int idx = it * 256 + threadIdx.x;
            int j = idx >> 4;            // 0..63
            int p = idx & 15;            // i-pair
            int jj = j0 + j;
            if (jj < N_PTS) {
                __half2 h = __halves2half2(__float2half(tile[2 * p][j]),
                                           __float2half(tile[2 * p + 1][j]));
                *reinterpret_cast<__half2*>(decT + (size_t)jj * 32 + 2 * p) = h;
            }
        }
    }
}

// ---------------------------------------------------------------------------
// K_tab (1 block): build invFG[512] (f32) and invHLG[256] (packed h2) ONCE.
// invF[c*32+i] = 1/(sigmoid(enc.bw_w[i*16+c]+b)*MU/60)^2
// ---------------------------------------------------------------------------
__global__ __launch_bounds__(256) void k_tab(const float* __restrict__ enc_g,
                                             const float* __restrict__ bw_w,
                                             const float* __restrict__ bw_b,
                                             float* __restrict__ invFG,
                                             h2* __restrict__ invHLG) {
    __shared__ float encL[32];
    __shared__ float invF[512];
    if (threadIdx.x < 32) encL[threadIdx.x] = enc_g[threadIdx.x];
    __syncthreads();
    for (int r = threadIdx.x; r < 512; r += 256) {
        int i = r >> 4, c = r & 15;
        const float4* wr4 = reinterpret_cast<const float4*>(bw_w + (size_t)r * 32);
        float z = bw_b[r];
        #pragma unroll
        for (int p4 = 0; p4 < 8; ++p4) {
            float4 wv = wr4[p4];
            z = fmaf(encL[4 * p4 + 0], wv.x, z);
            z = fmaf(encL[4 * p4 + 1], wv.y, z);
            z = fmaf(encL[4 * p4 + 2], wv.z, z);
            z = fmaf(encL[4 * p4 + 3], wv.w, z);
        }
        float s = 1.f / (1.f + __expf(-z));
        float wmu = s * (MU_F / 60.0f);
        float iv = 1.f / (wmu * wmu);
        invF[c * 32 + i] = iv;
        invFG[c * 32 + i] = iv;
    }
    __syncthreads();
    {
        int t = threadIdx.x;             // 16c x 4q x 4tt
        int c = t >> 4, q = (t >> 2) & 3, tt = t & 3;
        int i0 = q * 8 + 2 * tt;
        invHLG[t] = h2pack(fminf(invF[c * 32 + i0], 6.0e4f),
                           fminf(invF[c * 32 + i0 + 1], 6.0e4f));
    }
}

// ---------------------------------------------------------------------------
// K2: S pass. 1024 blocks x 98 pts, cell-ownership (thread owns 4 cells);
// epilogue atomicAdd into replica blockIdx&7 (round-11 contention fix).
// ---------------------------------------------------------------------------
__global__ __launch_bounds__(256, 8) void k_S(const float* __restrict__ invFG,
                                              const float* __restrict__ nd,
                                              const int* __restrict__ labels,
                                              float* __restrict__ S8) {
    __shared__ float invF[512];
    if (threadIdx.x < 128)
        reinterpret_cast<float4*>(invF)[threadIdx.x] =
            reinterpret_cast<const float4*>(invFG)[threadIdx.x];
    __syncthreads();

    int kk = threadIdx.x & 31;
    int ig = threadIdx.x >> 5;           // 0..7
    int start = blockIdx.x * S_PCH;
    int jend = min(start + S_PCH, N_PTS);

    float a0 = 0.f, a1 = 0.f, a2 = 0.f, a3 = 0.f;

    auto ld4 = [&](int jbase, float* d, int* cc) {
        #pragma unroll
        for (int u = 0; u < 4; ++u) {
            int j = jbase + u;
            int jc = min(j, N_PTS - 1);
            float dv = __builtin_nontemporal_load(&nd[(size_t)jc * 32 + kk]);
            cc[u] = labels[jc];
            d[u] = (j < jend) ? dv : 1.0e15f;   // pad -> w == 0 exactly
        }
    };
    float dA[4], dB[4], dC[4]; int cA[4], cB[4], cC[4];
    ld4(start, dA, cA);
    ld4(start + 4, dB, cB);
    for (int jj = start; jj < jend; jj += 4) {
        ld4(jj + 8, dC, cC);
        #pragma unroll
        for (int u = 0; u < 4; ++u) {
            float4 iv = *reinterpret_cast<const float4*>(&invF[cA[u] * 32 + ig * 4]);
            float d2 = dA[u] * dA[u];
            a0 += fmaxf(fmaf(d2, -iv.x, 1.f), 0.f);
            a1 += fmaxf(fmaf(d2, -iv.y, 1.f), 0.f);
            a2 += fmaxf(fmaf(d2, -iv.z, 1.f), 0.f);
            a3 += fmaxf(fmaf(d2, -iv.w, 1.f), 0.f);
        }
        #pragma unroll
        for (int u = 0; u < 4; ++u) {
            dA[u] = dB[u]; cA[u] = cB[u];
            dB[u] = dC[u]; cB[u] = cC[u];
        }
    }

    float* Sc = S8 + (size_t)(blockIdx.x & (NCOPY - 1)) * 1024;
    int cell = (ig * 4) * 32 + kk;
    atomicAdd(&Sc[cell], a0);
    atomicAdd(&Sc[cell + 32], a1);
    atomicAdd(&Sc[cell + 64], a2);
    atomicAdd(&Sc[cell + 96], a3);
}

// ---------------------------------------------------------------------------
// K4 (main): single full pass, TWO independent pairs per wave-iteration
// (within-iteration ILP — the only scheme the scheduler can't sink).
// (256,4), grid 1024. Measured best: 46.5us.
// ---------------------------------------------------------------------------
__global__ __launch_bounds__(256, 4) void k_main(const h2* __restrict__ invHLG,
                                                 const float* __restrict__ enc_g,
                                                 const float* __restrict__ S8,
                                                 const float* __restrict__ nd,
                                                 const int* __restrict__ nid,
                                                 const int* __restrict__ labels,
                                                 const __half* __restrict__ decT,
                                                 float* __restrict__ out) {
    __shared__ h2 invHL[256];            // [c][q][t] : c*16 + q*4 + t
    __shared__ float Sred[1024];
    if (threadIdx.x < 64)                // 1KB coalesced copy
        reinterpret_cast<uint4*>(invHL)[threadIdx.x] =
            reinterpret_cast<const uint4*>(invHLG)[threadIdx.x];
    for (int t = threadIdx.x; t < 1024; t += 256) {
        float s = 0.f;
        #pragma unroll
        for (int c = 0; c < NCOPY; ++c)
            s += S8[(size_t)c * 1024 + t];
        Sred[t] = s;
    }
    __syncthreads();

    int lane = threadIdx.x & 63;
    int R = lane >> 2;                   // 0..15
    int q = lane & 3;                    // i-quarter / row quad

    // per-thread E tables: ELf[t] = enc[t>>5]/S[t]*E_SCALE; (i0*32+R)>>5 == i0.
    h2 EhA[4], EhB[4];
    #pragma unroll
    for (int t = 0; t < 4; ++t) {
        int i0 = q * 8 + 2 * t;
        float e0 = enc_g[i0], e1 = enc_g[i0 + 1];
        float sA0 = Sred[i0 * 32 + R],      sA1 = Sred[(i0 + 1) * 32 + R];
        float sB0 = Sred[i0 * 32 + R + 16], sB1 = Sred[(i0 + 1) * 32 + R + 16];
        EhA[t] = h2pack(e0 / sA0 * E_SCALE, e1 / sA1 * E_SCALE);
        EhB[t] = h2pack(e0 / sB0 * E_SCALE, e1 / sB1 * E_SCALE);
    }
    const h2 zero2 = h2pack(0.f, 0.f);
    const h2 one2 = h2pack(1.f, 1.f);

    int w = threadIdx.x >> 6;            // wave 0..3
    int start = blockIdx.x * M_CH;
    int pend = min(start + M_CH, NPAIRS);
    const uint4* decQ = reinterpret_cast<const uint4*>(decT);

    auto load_ldd = [&](int jp0, int jp1, int* id, float* dd) {
        #pragma unroll
        for (int s = 0; s < 4; ++s) {
            size_t idx = (size_t)((s >> 1) ? jp1 : jp0) * 32 + (s & 1) * 16 + R;
            id[s] = __builtin_nontemporal_load(&nid[idx]);
            dd[s] = __builtin_nontemporal_load(&nd[idx]);
        }
    };
    auto load_ih = [&](int c0, int c1, h2* ih0, h2* ih1) {
        uint4 a = *reinterpret_cast<const uint4*>(&invHL[c0 * 16 + q * 4]);
        uint4 bq = *reinterpret_cast<const uint4*>(&invHL[c1 * 16 + q * 4]);
        ih0[0] = __builtin_bit_cast(h2, a.x);  ih0[1] = __builtin_bit_cast(h2, a.y);
        ih0[2] = __builtin_bit_cast(h2, a.z);  ih0[3] = __builtin_bit_cast(h2, a.w);
        ih1[0] = __builtin_bit_cast(h2, bq.x); ih1[1] = __builtin_bit_cast(h2, bq.y);
        ih1[2] = __builtin_bit_cast(h2, bq.z); ih1[3] = __builtin_bit_cast(h2, bq.w);
    };

    for (int p = start + w; p < pend; p += 8) {
        bool has2 = (p + 4) < pend;
        int p2 = has2 ? (p + 4) : p;     // clamp: compute-but-don't-write
        int jA0 = 2 * p,  jA1 = jA0 + 1; // N even -> j1 always valid
        int jB0 = 2 * p2, jB1 = jB0 + 1;

        int cA0 = labels[jA0], cA1 = labels[jA1];
        int cB0 = labels[jB0], cB1 = labels[jB1];
        int idA[4], idB[4]; float ddA[4], ddB[4];
        load_ldd(jA0, jA1, idA, ddA);
        load_ldd(jB0, jB1, idB, ddB);
        uint4 rA[4], rB[4];
        #pragma unroll
        for (int s = 0; s < 4; ++s) {
            rA[s] = decQ[(size_t)idA[s] * 4 + q];
            rB[s] = decQ[(size_t)idB[s] * 4 + q];
        }
        h2 ihA0[4], ihA1[4], ihB0[4], ihB1[4];
        load_ih(cA0, cA1, ihA0, ihA1);
        load_ih(cB0, cB1, ihB0, ihB1);

        h2 mdA0, mdA1, mdA2, mdA3, mdB0, mdB1, mdB2, mdB3;
        {
            float d0 = ddA[0] * ddA[0], d1 = ddA[1] * ddA[1];
            float d2 = ddA[2] * ddA[2], d3 = ddA[3] * ddA[3];
            mdA0 = h2pack(-d0, -d0); mdA1 = h2pack(-d1, -d1);
            mdA2 = h2pack(-d2, -d2); mdA3 = h2pack(-d3, -d3);
            float e0 = ddB[0] * ddB[0], e1 = ddB[1] * ddB[1];
            float e2 = ddB[2] * ddB[2], e3 = ddB[3] * ddB[3];
            mdB0 = h2pack(-e0, -e0); mdB1 = h2pack(-e1, -e1);
            mdB2 = h2pack(-e2, -e2); mdB3 = h2pack(-e3, -e3);
        }

        float a0 = 0.f, a1 = 0.f, a2 = 0.f, a3 = 0.f;
        float b0 = 0.f, b1 = 0.f, b2 = 0.f, b3 = 0.f;
        #pragma unroll
        for (int t = 0; t < 4; ++t) {
            uint wA0 = (t == 0) ? rA[0].x : (t == 1) ? rA[0].y : (t == 2) ? rA[0].z : rA[0].w;
            uint wA1 = (t == 0) ? rA[1].x : (t == 1) ? rA[1].y : (t == 2) ? rA[1].z : rA[1].w;
            uint wA2 = (t == 0) ? rA[2].x : (t == 1) ? rA[2].y : (t == 2) ? rA[2].z : rA[2].w;
            uint wA3 = (t == 0) ? rA[3].x : (t == 1) ? rA[3].y : (t == 2) ? rA[3].z : rA[3].w;
            uint wB0 = (t == 0) ? rB[0].x : (t == 1) ? rB[0].y : (t == 2) ? rB[0].z : rB[0].w;
            uint wB1 = (t == 0) ? rB[1].x : (t == 1) ? rB[1].y : (t == 2) ? rB[1].z : rB[1].w;
            uint wB2 = (t == 0) ? rB[2].x : (t == 1) ? rB[2].y : (t == 2) ? rB[2].z : rB[2].w;
            uint wB3 = (t == 0) ? rB[3].x : (t == 1) ? rB[3].y : (t == 2) ? rB[3].z : rB[3].w;
            {
                h2 wv = h2max(h2fma(mdA0, ihA0[t], one2), zero2);
                a0 = fdot2f(wv * EhA[t], __builtin_bit_cast(h2, wA0), a0);
            }
            {
                h2 wv = h2max(h2fma(mdA1, ihA0[t], one2), zero2);
                a1 = fdot2f(wv * EhB[t], __builtin_bit_cast(h2, wA1), a1);
            }
            {
                h2 wv = h2max(h2fma(mdA2, ihA1[t], one2), zero2);
                a2 = fdot2f(wv * EhA[t], __builtin_bit_cast(h2, wA2), a2);
            }
            {
                h2 wv = h2max(h2fma(mdA3, ihA1[t], one2), zero2);
                a3 = fdot2f(wv * EhB[t], __builtin_bit_cast(h2, wA3), a3);
            }
            {
                h2 wv = h2max(h2fma(mdB0, ihB0[t], one2), zero2);
                b0 = fdot2f(wv * EhA[t], __builtin_bit_cast(h2, wB0), b0);
            }
            {
                h2 wv = h2max(h2fma(mdB1, ihB0[t], one2), zero2);
                b1 = fdot2f(wv * EhB[t], __builtin_bit_cast(h2, wB1), b1);
            }
            {
                h2 wv = h2max(h2fma(mdB2, ihB1[t], one2), zero2);
                b2 = fdot2f(wv * EhA[t], __builtin_bit_cast(h2, wB2), b2);
            }
            {
                h2 wv = h2max(h2fma(mdB3, ihB1[t], one2), zero2);
                b3 = fdot2f(wv * EhB[t], __builtin_bit_cast(h2, wB3), b3);
            }
        }
        float u = a0 + a1;               // jA0 partial
        float v = a2 + a3;               // jA1 partial
        float u2 = b0 + b1;              // jB0 partial
        float v2 = b2 + b3;              // jB1 partial
        #pragma unroll
        for (int off = 32; off > 0; off >>= 1) {
            u += __shfl_xor(u, off);
            v += __shfl_xor(v, off);
            u2 += __shfl_xor(u2, off);
            v2 += __shfl_xor(v2, off);
        }
        if (lane == 0) {
            out[jA0] = u * E_SCALE_INV;
            if (has2) out[jB0] = u2 * E_SCALE_INV;
        }
        if (lane == 32) {
            out[jA1] = v * E_SCALE_INV;
            if (has2) out[jB1] = v2 * E_SCALE_INV;
        }
    }
}

// ---------------------------------------------------------------------------
extern "C" void kernel_launch(void* const* d_in, const int* in_sizes, int n_in,
                              void* d_out, int out_size, void* d_ws, size_t ws_size,
                              hipStream_t stream) {
    const float* x     = (const float*)d_in[0];
    const float* enc_w = (const float*)d_in[1];
    const float* enc_b = (const float*)d_in[2];
    const float* dec   = (const float*)d_in[3];
    const float* bw_w  = (const float*)d_in[4];
    const float* bw_b  = (const float*)d_in[5];
    const float* nd    = (const float*)d_in[6];
    const int*   nid   = (const int*)d_in[7];
    const int*   labels= (const int*)d_in[8];
    float* out = (float*)d_out;

    char* ws = (char*)d_ws;
    float* enc    = (float*)(ws + 0);
    float* S8     = (float*)(ws + 128);
    float* invFG  = (float*)(ws + 32896);
    h2*    invHLG = (h2*)(ws + 34944);
    __half* decT  = (__half*)(ws + 532480);

    (void)hipMemsetAsync(d_ws, 0, 32896, stream);    // enc + S8
    k_prep_tr<<<dim3(ENC_BLKS + TR_BLKS), dim3(256), 0, stream>>>(
        x, enc_w, enc_b, enc, dec, decT);
    k_tab<<<dim3(1), dim3(256), 0, stream>>>(enc, bw_w, bw_b, invFG, invHLG);
    k_S<<<dim3(S_BLKS), dim3(256), 0, stream>>>(invFG, nd, labels, S8);
    k_main<<<dim3(M_BLKS), dim3(256), 0, stream>>>(invHLG, enc, S8, nd, nid,
                                                   labels, decT, out);
}